// Round 2
// baseline (982.882 us; speedup 1.0000x reference)
//
#include <hip/hip_runtime.h>
#include <math.h>

#define CAP 256   // padded-CSR capacity per node; deg ~ Poisson(64), P(>256) ~ 0

// ---------- small precompute kernels ----------

// WT[j][i] = W[i][j]  (128x128)
__global__ void k_transpose(const float* __restrict__ W, float* __restrict__ WT) {
    int j = blockIdx.x, i = threadIdx.x;
    WT[j * 128 + i] = W[i * 128 + j];
}

// Y[r,:] = X[r,:] @ W + b   (16 rows per block, 128 threads)
__global__ void k_rowproj(const float* __restrict__ X, const float* __restrict__ W,
                          const float* __restrict__ b, float* __restrict__ Y, int nrows) {
    __shared__ float xs[16][128];
    int tid = threadIdx.x;
    int r0 = blockIdx.x * 16;
    for (int t = 0; t < 16; ++t) {
        int r = r0 + t;
        xs[t][tid] = (r < nrows) ? X[(size_t)r * 128 + tid] : 0.f;
    }
    __syncthreads();
    float acc[16];
#pragma unroll
    for (int t = 0; t < 16; ++t) acc[t] = 0.f;
    for (int m = 0; m < 128; ++m) {
        float w = W[m * 128 + tid];
#pragma unroll
        for (int t = 0; t < 16; ++t) acc[t] += xs[t][m] * w;
    }
    float bb = b[tid];
    for (int t = 0; t < 16; ++t) {
        int r = r0 + t;
        if (r < nrows) Y[(size_t)r * 128 + tid] = acc[t] + bb;
    }
}

// qk[n][h][i] = sum_jj q[n][32h+jj] * Wk[i][32h+jj]   (via WkT for coalescing)
__global__ void k_qk(const float* __restrict__ q, const float* __restrict__ WkT,
                     float* __restrict__ qk, int nrows) {
    __shared__ float xs[16][128];
    int tid = threadIdx.x;
    int r0 = blockIdx.x * 16;
    for (int t = 0; t < 16; ++t) {
        int r = r0 + t;
        xs[t][tid] = (r < nrows) ? q[(size_t)r * 128 + tid] : 0.f;
    }
    __syncthreads();
    for (int h = 0; h < 4; ++h) {
        float acc[16];
#pragma unroll
        for (int t = 0; t < 16; ++t) acc[t] = 0.f;
        for (int jj = 0; jj < 32; ++jj) {
            float w = WkT[(h * 32 + jj) * 128 + tid];
#pragma unroll
            for (int t = 0; t < 16; ++t) acc[t] += xs[t][h * 32 + jj] * w;
        }
        for (int t = 0; t < 16; ++t) {
            int r = r0 + t;
            if (r < nrows) qk[((size_t)r * 4 + h) * 128 + tid] = acc[t];
        }
    }
}

// cb[n][h] = sum_jj q[n][32h+jj] * bk[32h+jj]
__global__ void k_cb(const float* __restrict__ q, const float* __restrict__ bk,
                     float* __restrict__ cb, int nh) {
    int t = blockIdx.x * 256 + threadIdx.x;
    if (t >= nh) return;
    int n = t >> 2, h = t & 3;
    float s = 0.f;
    for (int jj = 0; jj < 32; ++jj) s += q[(size_t)n * 128 + h * 32 + jj] * bk[h * 32 + jj];
    cb[t] = s;
}

// M[h][i][j] = sum_d Wv[i][32h+d] * Wo[32h+d][j]
__global__ void k_M(const float* __restrict__ Wv, const float* __restrict__ Wo,
                    float* __restrict__ M) {
    int hi = blockIdx.x;            // 0..511 = h*128+i
    int j = threadIdx.x;
    int h = hi >> 7, i = hi & 127;
    float s = 0.f;
    for (int d = 0; d < 32; ++d) s += Wv[i * 128 + h * 32 + d] * Wo[(h * 32 + d) * 128 + j];
    M[hi * 128 + j] = s;
}

// bvWo[j] = sum_k bv[k]*Wo[k][j]
__global__ void k_bvwo(const float* __restrict__ bv, const float* __restrict__ Wo,
                       float* __restrict__ bvWo) {
    int j = threadIdx.x;
    float s = 0.f;
    for (int k2 = 0; k2 < 128; ++k2) s += bv[k2] * Wo[k2 * 128 + j];
    bvWo[j] = s;
}

// padded-CSR build: histogram + scatter in one pass
__global__ void k_build(const int* __restrict__ dst, int* __restrict__ counts,
                        int* __restrict__ padded, int E) {
    int e = blockIdx.x * 256 + threadIdx.x;
    if (e >= E) return;
    int d = dst[e];
    int slot = atomicAdd(&counts[d], 1);
    if (slot < CAP) padded[(size_t)d * CAP + slot] = e;
}

// ---------- main per-node kernel: score -> softmax -> aggregate ----------
__launch_bounds__(256)
__global__ void k_main(const float* __restrict__ k_edges, const float* __restrict__ v_edges,
                       const int* __restrict__ padded, const int* __restrict__ counts,
                       const float* __restrict__ qk, const float* __restrict__ cb,
                       float* __restrict__ U) {
    int n = blockIdx.x;
    int tid = threadIdx.x;
    int w = tid >> 6, l = tid & 63;
    int deg = counts[n];
    if (deg > CAP) deg = CAP;
    if (deg == 0) {
        *(float2*)&U[(size_t)n * 512 + tid * 2] = make_float2(0.f, 0.f);
        return;
    }
    const float scale = 0.17677669529663687f;  // 1/sqrt(32)

    float2 qkr[4];
    float cbv[4];
#pragma unroll
    for (int h = 0; h < 4; ++h) {
        qkr[h] = *(const float2*)&qk[((size_t)n * 4 + h) * 128 + 2 * l];
        cbv[h] = cb[n * 4 + h];
    }

    __shared__ float sc[CAP * 4];       // per-edge per-head score -> ex
    __shared__ float wred[4][4];        // wave max
    __shared__ float wred2[4][4];       // wave sum
    __shared__ float u_lds[4 * 512];    // per-wave partial U

    // ---- phase 1: scores + running max (wave per edge) ----
    float wmax[4] = {-1e30f, -1e30f, -1e30f, -1e30f};
    for (int j = w; j < deg; j += 4) {
        int e = padded[(size_t)n * CAP + j];
        float2 kv = *(const float2*)&k_edges[(size_t)e * 128 + 2 * l];
        float p[4];
#pragma unroll
        for (int h = 0; h < 4; ++h) p[h] = kv.x * qkr[h].x + kv.y * qkr[h].y;
#pragma unroll
        for (int off = 32; off >= 1; off >>= 1) {
#pragma unroll
            for (int h = 0; h < 4; ++h) p[h] += __shfl_xor(p[h], off);
        }
        float s4[4];
#pragma unroll
        for (int h = 0; h < 4; ++h) {
            s4[h] = (p[h] + cbv[h]) * scale;
            wmax[h] = fmaxf(wmax[h], s4[h]);
        }
        if (l == 0) *(float4*)&sc[j * 4] = make_float4(s4[0], s4[1], s4[2], s4[3]);
    }
    if (l == 0) {
#pragma unroll
        for (int h = 0; h < 4; ++h) wred[w][h] = wmax[h];
    }
    __syncthreads();
    float gmax[4];
#pragma unroll
    for (int h = 0; h < 4; ++h)
        gmax[h] = fmaxf(fmaxf(wred[0][h], wred[1][h]), fmaxf(wred[2][h], wred[3][h]));

    // ---- phase 2: exp + denominator (thread per edge) ----
    float ps[4] = {0.f, 0.f, 0.f, 0.f};
    if (tid < deg) {
        float4 s4 = *(float4*)&sc[tid * 4];
        float e0 = __expf(s4.x - gmax[0]);
        float e1 = __expf(s4.y - gmax[1]);
        float e2 = __expf(s4.z - gmax[2]);
        float e3 = __expf(s4.w - gmax[3]);
        *(float4*)&sc[tid * 4] = make_float4(e0, e1, e2, e3);
        ps[0] = e0; ps[1] = e1; ps[2] = e2; ps[3] = e3;
    }
#pragma unroll
    for (int off = 32; off >= 1; off >>= 1) {
#pragma unroll
        for (int h = 0; h < 4; ++h) ps[h] += __shfl_xor(ps[h], off);
    }
    if (l == 0) {
#pragma unroll
        for (int h = 0; h < 4; ++h) wred2[w][h] = ps[h];
    }
    __syncthreads();
    float inv[4];
#pragma unroll
    for (int h = 0; h < 4; ++h)
        inv[h] = 1.f / (wred2[0][h] + wred2[1][h] + wred2[2][h] + wred2[3][h]);

    // ---- phase 3: aggregate attn-weighted v rows (wave per edge) ----
    float ax[4] = {0.f, 0.f, 0.f, 0.f}, ay[4] = {0.f, 0.f, 0.f, 0.f};
    for (int j = w; j < deg; j += 4) {
        int e = padded[(size_t)n * CAP + j];
        float2 vv = *(const float2*)&v_edges[(size_t)e * 128 + 2 * l];
        float4 a4 = *(float4*)&sc[j * 4];
        float a[4] = {a4.x, a4.y, a4.z, a4.w};
#pragma unroll
        for (int h = 0; h < 4; ++h) {
            float t = a[h] * inv[h];
            ax[h] += t * vv.x;
            ay[h] += t * vv.y;
        }
    }
#pragma unroll
    for (int h = 0; h < 4; ++h)
        *(float2*)&u_lds[w * 512 + h * 128 + 2 * l] = make_float2(ax[h], ay[h]);
    __syncthreads();
    int i0 = tid * 2;
    float s0 = u_lds[i0] + u_lds[512 + i0] + u_lds[1024 + i0] + u_lds[1536 + i0];
    float s1 = u_lds[i0 + 1] + u_lds[512 + i0 + 1] + u_lds[1024 + i0 + 1] + u_lds[1536 + i0 + 1];
    *(float2*)&U[(size_t)n * 512 + i0] = make_float2(s0, s1);
}

// ---------- output projection: out[n,:] = U[n,:,:] : M + [deg>0]*bvWo + bo ----------
__global__ void k_out(const float* __restrict__ U, const float* __restrict__ M,
                      const float* __restrict__ bvWo, const float* __restrict__ bo,
                      const int* __restrict__ counts, float* __restrict__ out, int nrows) {
    __shared__ float us[16 * 512];  // 32 KiB
    int tid = threadIdx.x;
    int r0 = blockIdx.x * 16;
    for (int t = 0; t < 16; ++t) {
        int r = r0 + t;
        for (int c = 0; c < 4; ++c)
            us[t * 512 + c * 128 + tid] = (r < nrows) ? U[(size_t)r * 512 + c * 128 + tid] : 0.f;
    }
    __syncthreads();
    float acc[16];
#pragma unroll
    for (int t = 0; t < 16; ++t) acc[t] = 0.f;
    for (int hi = 0; hi < 512; ++hi) {
        float m = M[hi * 128 + tid];
#pragma unroll
        for (int t = 0; t < 16; ++t) acc[t] += us[t * 512 + hi] * m;
    }
    for (int t = 0; t < 16; ++t) {
        int r = r0 + t;
        if (r < nrows)
            out[(size_t)r * 128 + tid] =
                acc[t] + ((counts[r] > 0) ? bvWo[tid] : 0.f) + bo[tid];
    }
}

extern "C" void kernel_launch(void* const* d_in, const int* in_sizes, int n_in,
                              void* d_out, int out_size, void* d_ws, size_t ws_size,
                              hipStream_t stream) {
    const float* q_nodes = (const float*)d_in[0];
    const float* k_edges = (const float*)d_in[1];
    const float* v_edges = (const float*)d_in[2];
    const float* Wq = (const float*)d_in[3];
    const float* bq = (const float*)d_in[4];
    const float* Wk = (const float*)d_in[5];
    const float* bk = (const float*)d_in[6];
    const float* Wv = (const float*)d_in[7];
    const float* bv = (const float*)d_in[8];
    const float* Wo = (const float*)d_in[9];
    const float* bo = (const float*)d_in[10];
    const int* ei = (const int*)d_in[11];   // (2,E) row-major: first E = dst
    float* out = (float*)d_out;

    int N = in_sizes[0] / 128;
    int E = in_sizes[1] / 128;

    char* ws = (char*)d_ws;
    size_t off = 0;
    auto alloc = [&](size_t bytes) {
        void* p = ws + off;
        off += (bytes + 255) & ~(size_t)255;
        return p;
    };
    float* q    = (float*)alloc((size_t)N * 128 * 4);
    float* qk   = (float*)alloc((size_t)N * 512 * 4);
    float* cbuf = (float*)alloc((size_t)N * 4 * 4);
    float* WkT  = (float*)alloc(16384 * 4);
    float* M    = (float*)alloc(65536 * 4);
    float* bvWo = (float*)alloc(128 * 4);
    float* U    = (float*)alloc((size_t)N * 512 * 4);
    int* counts = (int*)alloc((size_t)N * 4);
    int* padded = (int*)alloc((size_t)N * CAP * 4);

    hipMemsetAsync(counts, 0, (size_t)N * 4, stream);

    int nb16 = (N + 15) / 16;
    k_transpose<<<128, 128, 0, stream>>>(Wk, WkT);
    k_rowproj<<<nb16, 128, 0, stream>>>(q_nodes, Wq, bq, q, N);
    k_qk<<<nb16, 128, 0, stream>>>(q, WkT, qk, N);
    k_cb<<<(N * 4 + 255) / 256, 256, 0, stream>>>(q, bk, cbuf, N * 4);
    k_M<<<512, 128, 0, stream>>>(Wv, Wo, M);
    k_bvwo<<<1, 128, 0, stream>>>(bv, Wo, bvWo);
    k_build<<<(E + 255) / 256, 256, 0, stream>>>(ei, counts, padded, E);
    k_main<<<N, 256, 0, stream>>>(k_edges, v_edges, padded, counts, qk, cbuf, U);
    k_out<<<nb16, 128, 0, stream>>>(U, M, bvWo, bo, counts, out, N);
}